// Round 11
// baseline (622.133 us; speedup 1.0000x reference)
//
#include <hip/hip_runtime.h>
#include <hip/hip_fp16.h>
#include <cstdint>

// Problem constants (B=4, S=4096, D=1024)
#define NRALL 16384
#define DM    1024
#define DI    2048
#define SEQL  4096

typedef _Float16 f16;
typedef _Float16 f16x8 __attribute__((ext_vector_type(8)));
typedef _Float16 f16x4 __attribute__((ext_vector_type(4)));
typedef float    f32x4 __attribute__((ext_vector_type(4)));

__device__ __forceinline__ float phi_f(float t)  { return t > 0.0f ? t + 1.0f : __expf(t); }
__device__ __forceinline__ float silu_f(float t) { return t / (1.0f + __expf(-t)); }

#define GLDS16(g, l)                                                            \
    __builtin_amdgcn_global_load_lds(                                           \
        (const __attribute__((address_space(1))) void*)(g),                     \
        (__attribute__((address_space(3))) void*)(l), 16, 0, 0)

#define FMA4(dst, s, vv)                      \
    dst.x = fmaf((s), (vv).x, dst.x);         \
    dst.y = fmaf((s), (vv).y, dst.y);         \
    dst.z = fmaf((s), (vv).z, dst.z);         \
    dst.w = fmaf((s), (vv).w, dst.w);

// ---------------- 1. rmsnorm -> f16 --------------------------------------------
__global__ __launch_bounds__(256) void rmsnorm_k(const float* __restrict__ x,
                                                 const float* __restrict__ nw,
                                                 f16* __restrict__ xn)
{
    const int r = blockIdx.x, t = threadIdx.x;
    const float4 v = *(const float4*)(x + (size_t)r * DM + t * 4);
    float s = v.x * v.x + v.y * v.y + v.z * v.z + v.w * v.w;
#pragma unroll
    for (int m = 1; m < 64; m <<= 1) s += __shfl_xor(s, m);
    __shared__ float ws4[4];
    if ((t & 63) == 0) ws4[t >> 6] = s;
    __syncthreads();
    const float tot = ws4[0] + ws4[1] + ws4[2] + ws4[3];
    const float sc = rsqrtf(tot * (1.0f / DM) + 1e-5f);
    const float4 w = *(const float4*)(nw + t * 4);
    f16x4 o;
    o[0] = (f16)(v.x * sc * w.x); o[1] = (f16)(v.y * sc * w.y);
    o[2] = (f16)(v.z * sc * w.z); o[3] = (f16)(v.w * sc * w.w);
    *(f16x4*)(xn + (size_t)r * DM + t * 4) = o;
}

// ---------------- 2. merged weight format (all 7 weights, one launch) -----------
// Layout per (kt, kh): Ntot x 64B; chunk (n, slot) holds 8 f16 of
// k = kt*64 + kh*32 + c2*8 .. +7 where c2 = slot ^ ((n>>1)&3)  (2-way-free swizzle).
__device__ __forceinline__ void wfmt_one(const float* __restrict__ W, char* __restrict__ fmt,
                                         int n, int kt, int Nw, int Ntot, int noff)
{
    const int ng = noff + n;
#pragma unroll
    for (int kh = 0; kh < 2; ++kh) {
        char* o = fmt + ((size_t)(kt * 2 + kh) * Ntot + ng) * 64;
#pragma unroll
        for (int c2 = 0; c2 < 4; ++c2) {
            f16x8 p;
#pragma unroll
            for (int j = 0; j < 8; ++j)
                p[j] = (f16)W[(size_t)(kt * 64 + kh * 32 + c2 * 8 + j) * Nw + n];
            *(f16x8*)(o + ((c2 ^ ((ng >> 1) & 3)) << 4)) = p;
        }
    }
}

__global__ __launch_bounds__(256) void wfmt_all_k(const float* __restrict__ w_up,
                                                  const float* __restrict__ w_gate,
                                                  const float* __restrict__ w_down,
                                                  const float* __restrict__ wq,
                                                  const float* __restrict__ wk,
                                                  const float* __restrict__ wv,
                                                  const float* __restrict__ wo,
                                                  char* __restrict__ fmtUG,
                                                  char* __restrict__ fmtD,
                                                  char* __restrict__ fmtQKV,
                                                  char* __restrict__ fmtO)
{
    int id = blockIdx.x;
    const int t = threadIdx.x;
    if (id < 128) { wfmt_one(w_up,   fmtUG,  (id % 8) * 256 + t, id / 8, DI, 4096, 0);    return; }
    id -= 128;
    if (id < 128) { wfmt_one(w_gate, fmtUG,  (id % 8) * 256 + t, id / 8, DI, 4096, 2048); return; }
    id -= 128;
    if (id < 128) { wfmt_one(w_down, fmtD,   (id % 4) * 256 + t, id / 4, DM, 1024, 0);    return; }
    id -= 128;
    if (id < 64)  { wfmt_one(wq,     fmtQKV, (id % 4) * 256 + t, id / 4, DM, 3072, 0);    return; }
    id -= 64;
    if (id < 64)  { wfmt_one(wk,     fmtQKV, (id % 4) * 256 + t, id / 4, DM, 3072, 1024); return; }
    id -= 64;
    if (id < 64)  { wfmt_one(wv,     fmtQKV, (id % 4) * 256 + t, id / 4, DM, 3072, 2048); return; }
    id -= 64;
    wfmt_one(wo, fmtO, (id % 4) * 256 + t, id / 4, DM, 1024, 0);
}

// ---------------- 3. 256x256 MFMA GEMM, 4 merged phases / 2 K-tiles -------------
// 512 thr = 8 waves (2m x 4n), BK=64, LDS 128KB: {A,B} x 2buf x 2 k-halves.
// Phase (p,ks): vmcnt(8) -> 12 ds_read (8 A-frags + 4 B-frags) -> stage 1 slot
// (A+B, 4 glds) -> barrier -> lgkm(0) -> setprio(1) 32 MFMA setprio(0) -> barrier.
// 32 MFMA/phase halves the per-phase overhead vs the 16-MFMA schedule (which
// measured 1312 cyc/phase vs 620 MFMA + 576 LDS demand).
// Stage map (iter i computes tiles 2i (buf0), 2i+1 (buf1)), slot = (buf,kh):
//  P0: read (0,k0)t2i   stage (1,k1)<-2i+1
//  P1: read (0,k1)t2i   stage (0,k0)<-2i+2
//  P2: read (1,k0)t2i+1 stage (0,k1)<-2i+2
//  P3: read (1,k1)t2i+1 stage (1,k0)<-2i+3
// RAW: each slot staged 3 phases before its reader; vmcnt(8) (= 2 phases x 4
// glds in flight) forces the 3-back stage complete before the reads issue.
// WAR: a slot's last reads complete at its reader-phase's lgkm(0), which is
// followed by that phase's trailing barrier; the overwriting stage issues in a
// later phase, strictly after that barrier.
#define PH(p, ks, SP, SKH, ST)                                                    \
    {                                                                             \
        asm volatile("s_waitcnt vmcnt(8)" ::: "memory");                          \
        __builtin_amdgcn_sched_barrier(0);                                        \
        _Pragma("unroll")                                                         \
        for (int q = 0; q < 8; ++q) {                                             \
            const int row = wm * 128 + q * 16 + lr16;                             \
            af[q] = *(const f16x8*)(ldsb + (p) * 32768 + (ks) * 16384             \
                    + row * 64 + ((kb ^ ((row >> 1) & 3)) << 4));                 \
        }                                                                         \
        _Pragma("unroll")                                                         \
        for (int q = 0; q < 4; ++q) {                                             \
            const int n = wn * 64 + q * 16 + lr16;                                \
            bf[q] = *(const f16x8*)(ldsb + 65536 + (p) * 32768 + (ks) * 16384     \
                    + n * 64 + ((kb ^ ((n >> 1) & 3)) << 4));                     \
        }                                                                         \
        STAGE_A(SP, SKH, ST);                                                     \
        STAGE_B(SP, SKH, ST);                                                     \
        __builtin_amdgcn_sched_barrier(0);                                        \
        __builtin_amdgcn_s_barrier();                                             \
        asm volatile("s_waitcnt lgkmcnt(0)" ::: "memory");                        \
        __builtin_amdgcn_sched_barrier(0);                                        \
        __builtin_amdgcn_s_setprio(1);                                            \
        _Pragma("unroll")                                                         \
        for (int q = 0; q < 8; ++q) {                                             \
            acc[q][0] = __builtin_amdgcn_mfma_f32_16x16x32_f16(af[q], bf[0], acc[q][0], 0, 0, 0); \
            acc[q][1] = __builtin_amdgcn_mfma_f32_16x16x32_f16(af[q], bf[1], acc[q][1], 0, 0, 0); \
            acc[q][2] = __builtin_amdgcn_mfma_f32_16x16x32_f16(af[q], bf[2], acc[q][2], 0, 0, 0); \
            acc[q][3] = __builtin_amdgcn_mfma_f32_16x16x32_f16(af[q], bf[3], acc[q][3], 0, 0, 0); \
        }                                                                         \
        __builtin_amdgcn_s_setprio(0);                                            \
        __builtin_amdgcn_sched_barrier(0);                                        \
        __builtin_amdgcn_s_barrier();                                             \
    }

template <int EPI>
__global__ __launch_bounds__(512, 2) void mg256_k(const f16* __restrict__ A, int lda,
                                                  const char* __restrict__ fmt,
                                                  void* __restrict__ Cv,
                                                  int N, int K, int gx,
                                                  const float* __restrict__ addx)
{
    __shared__ __align__(16) char ldsb[131072];

    const int t = threadIdx.x;
    int wid = blockIdx.x;
    { const int cpx = gridDim.x >> 3; wid = (wid & 7) * cpx + (wid >> 3); }  // XCD swizzle
    const int bx = wid % gx, by = wid / gx;
    const int bm = by * 256, bn = bx * 256;
    const int lane = t & 63, wv = t >> 6;
    const int wm = wv >> 2, wn = wv & 3;
    const int kb = lane >> 4, lr16 = lane & 15;
    const int NT = K >> 6;

    f32x4 acc[8][4];
#pragma unroll
    for (int i = 0; i < 8; ++i)
#pragma unroll
        for (int j = 0; j < 4; ++j) acc[i][j] = (f32x4)0.0f;

    auto STAGE_A = [&](int p, int kh, int kt) {
#pragma unroll
        for (int r = 0; r < 2; ++r) {
            const int idx = (r * 8 + wv) * 64;
            const int ii = idx + lane;
            const int row = ii >> 2, sl = ii & 3;
            const int c2 = sl ^ ((row >> 1) & 3);
            const f16* src = A + (size_t)(bm + row) * lda + kt * 64 + kh * 32 + c2 * 8;
            GLDS16(src, ldsb + p * 32768 + kh * 16384 + idx * 16);
        }
    };
    auto STAGE_B = [&](int p, int kh, int kt) {
#pragma unroll
        for (int r = 0; r < 2; ++r) {
            const int idx = (r * 8 + wv) * 64;
            const char* src = fmt + ((size_t)(kt * 2 + kh) * N + bn) * 64 + (size_t)(idx + lane) * 16;
            GLDS16(src, ldsb + 65536 + p * 32768 + kh * 16384 + idx * 16);
        }
    };

    f16x8 af[8], bf[4];

    // prologue: stage (0,k0),(0,k1)<-t0 and (1,k0)<-t1 (12 glds);
    // vmcnt(8) -> (0,k0) landed; (1,k1)<-t1 is staged in-loop at P0 of iter 0.
    const int T1 = NT > 1 ? 1 : 0;
    STAGE_A(0, 0, 0); STAGE_B(0, 0, 0);
    STAGE_A(0, 1, 0); STAGE_B(0, 1, 0);
    STAGE_A(1, 0, T1); STAGE_B(1, 0, T1);
    asm volatile("s_waitcnt vmcnt(8)" ::: "memory");
    __builtin_amdgcn_s_barrier();
    __builtin_amdgcn_sched_barrier(0);

    const int NI = NT >> 1;
    for (int i = 0; i < NI; ++i) {
        const int tA = 2 * i + 1 < NT ? 2 * i + 1 : NT - 1;
        const int tB = 2 * i + 2 < NT ? 2 * i + 2 : NT - 1;
        const int tC = 2 * i + 3 < NT ? 2 * i + 3 : NT - 1;
        PH(0, 0, 1, 1, tA)
        PH(0, 1, 0, 0, tB)
        PH(1, 0, 0, 1, tB)
        PH(1, 1, 1, 0, tC)
    }
    asm volatile("s_waitcnt vmcnt(0)" ::: "memory");  // drain DMA before LDS freed

    // ---- epilogue: C frag col=lane&15, row=(lane>>4)*4+r
#pragma unroll
    for (int fm = 0; fm < 8; ++fm) {
        const int row0 = bm + wm * 128 + fm * 16 + kb * 4;
#pragma unroll
        for (int fn = 0; fn < 4; ++fn) {
            const int col = bn + wn * 64 + fn * 16 + lr16;
#pragma unroll
            for (int r = 0; r < 4; ++r) {
                float o = acc[fm][fn][r];
                if (EPI == 1) {
                    if (col < DM) o = phi_f(o) * 0.125f;
                    else if (col < 2 * DM) o = phi_f(o);
                }
                if (EPI == 2) {
                    ((float*)Cv)[(size_t)(row0 + r) * N + col] =
                        o + addx[(size_t)(row0 + r) * N + col];
                } else {
                    ((f16*)Cv)[(size_t)(row0 + r) * N + col] = (f16)o;
                }
            }
        }
    }
}

// ---------------- 4. causal dwconv + silu + gate, rolling window ----------------
__global__ __launch_bounds__(256) void conv_gate_k(f16* __restrict__ upg,
                                                   const float* __restrict__ cw,
                                                   const float* __restrict__ cb)
{
    const int r0 = blockIdx.x * 16;
    const int c = threadIdx.x * 8;
    float bias[8];
    {
        const float4 b0 = *(const float4*)(cb + c);
        const float4 b1 = *(const float4*)(cb + c + 4);
        bias[0] = b0.x; bias[1] = b0.y; bias[2] = b0.z; bias[3] = b0.w;
        bias[4] = b1.x; bias[5] = b1.y; bias[6] = b1.z; bias[7] = b1.w;
    }
    float tap[8][4];
#pragma unroll
    for (int j = 0; j < 8; ++j)
        *(float4*)tap[j] = *(const float4*)(cw + (size_t)(c + j) * 4);

    const bool lead = (r0 & (SEQL - 1)) == 0;
    f16x8 w0, w1, w2;
    if (lead) {
        w0 = (f16x8)(f16)0; w1 = (f16x8)(f16)0; w2 = (f16x8)(f16)0;
    } else {
        w0 = *(const f16x8*)(upg + (size_t)(r0 - 3) * 4096 + c);
        w1 = *(const f16x8*)(upg + (size_t)(r0 - 2) * 4096 + c);
        w2 = *(const f16x8*)(upg + (size_t)(r0 - 1) * 4096 + c);
    }
#pragma unroll 4
    for (int i = 0; i < 16; ++i) {
        const size_t row = (size_t)(r0 + i);
        const f16x8 w3 = *(const f16x8*)(upg + row * 4096 + c);
        const f16x8 g  = *(const f16x8*)(upg + row * 4096 + 2048 + c);
        f16x8 o;
#pragma unroll
        for (int j = 0; j < 8; ++j) {
            float a = bias[j];
            a = fmaf((float)w0[j], tap[j][0], a);
            a = fmaf((float)w1[j], tap[j][1], a);
            a = fmaf((float)w2[j], tap[j][2], a);
            a = fmaf((float)w3[j], tap[j][3], a);
            o[j] = (f16)(silu_f((float)g[j]) * silu_f(a));
        }
        *(f16x8*)(upg + row * 4096 + 2048 + c) = o;
        w0 = w1; w1 = w2; w2 = w3;
    }
}

// ---------------- 5a. per-chunk outer products: G[b][h][ch] = K^T V (f16 out) ---
__global__ __launch_bounds__(256) void gscan_g_k(const f16* __restrict__ qkv,
                                                 f16* __restrict__ G)
{
    __shared__ float Ks[4096];
    __shared__ float Vs[4096];
    const int t = threadIdx.x, ch = blockIdx.x, h = blockIdx.y, b = blockIdx.z;
    const int r = t >> 2, c16 = (t & 3) * 16;
    const f16* kp = qkv + ((size_t)b * SEQL + ch * 64 + r) * 3072 + DM + h * 64 + c16;
#pragma unroll
    for (int i = 0; i < 2; ++i) {
        const f16x8 kv = *(const f16x8*)(kp + 8 * i);
        const f16x8 vv = *(const f16x8*)(kp + DM + 8 * i);
#pragma unroll
        for (int j = 0; j < 8; ++j) {
            Ks[r * 64 + c16 + 8 * i + j] = (float)kv[j];
            Vs[r * 64 + c16 + 8 * i + j] = (float)vv[j];
        }
    }
    __syncthreads();
    const int d4 = (t >> 4) * 4, e4 = (t & 15) * 4;
    float4 ag[4] = {};
#pragma unroll 4
    for (int c = 0; c < 64; ++c) {
        float ka[4];
        *(float4*)ka = *(const float4*)(Ks + c * 64 + d4);
        const float4 va = *(const float4*)(Vs + c * 64 + e4);
        FMA4(ag[0], ka[0], va);
        FMA4(ag[1], ka[1], va);
        FMA4(ag[2], ka[2], va);
        FMA4(ag[3], ka[3], va);
    }
    f16* go = G + (((size_t)b * 16 + h) * 64 + ch) * 4096 + d4 * 64 + e4;
#pragma unroll
    for (int i = 0; i < 4; ++i) {
        f16x4 o;
        o[0] = (f16)ag[i].x; o[1] = (f16)ag[i].y;
        o[2] = (f16)ag[i].z; o[3] = (f16)ag[i].w;
        *(f16x4*)(go + i * 64) = o;
    }
}

// ---------------- 5b. in-place exclusive prefix over chunks (f16, fp32 carry) ---
__global__ __launch_bounds__(256) void gprefix_k(f16* __restrict__ G)
{
    const int bh = blockIdx.x >> 4, sl = blockIdx.x & 15;
    const int idx = sl * 256 + threadIdx.x;
    float run = 0.0f;
    f16* p = G + (size_t)bh * 64 * 4096 + idx;
#pragma unroll 4
    for (int ch = 0; ch < 64; ++ch) {
        const float g = (float)*p;
        *p = (f16)run;
        run += g;
        p += 4096;
    }
}

// ---------------- 5c. per-chunk read: y = q*M_excl + tril(q k^T) v --------------
__global__ __launch_bounds__(256) void gscan_y_k(const f16* __restrict__ qkv,
                                                 const f16* __restrict__ G,
                                                 f16* __restrict__ y)
{
    __shared__ float qT[4096];   // qT[d][c]; later scT[e][c]
    __shared__ float Kd[4096];   // Kd[d][e] = K[e][d]
    __shared__ float Vs[4096];
    __shared__ float Ms[4096];
    const int t = threadIdx.x, ch = blockIdx.x, h = blockIdx.y, b = blockIdx.z;
    const int r = t >> 2, c16 = (t & 3) * 16;
    const f16* qp = qkv + ((size_t)b * SEQL + ch * 64 + r) * 3072 + h * 64 + c16;
#pragma unroll
    for (int i = 0; i < 2; ++i) {
        const f16x8 qv = *(const f16x8*)(qp + 8 * i);
        const f16x8 kv = *(const f16x8*)(qp + DM + 8 * i);
        const f16x8 vv = *(const f16x8*)(qp + 2 * DM + 8 * i);
#pragma unroll
        for (int j = 0; j < 8; ++j) {
            qT[(c16 + 8 * i + j) * 64 + r] = (float)qv[j];
            Kd[(c16 + 8 * i + j) * 64 + r] = (float)kv[j];
            Vs[r * 64 + c16 + 8 * i + j] = (float)vv[j];
        }
    }
    const f16* mg = G + (((size_t)b * 16 + h) * 64 + ch) * 4096;
#pragma unroll
    for (int i = 0; i < 2; ++i) {
        const f16x8 mv = *(const f16x8*)(mg + t * 16 + 8 * i);
#pragma unroll
        for (int j = 0; j < 8; ++j) Ms[t * 16 + 8 * i + j] = (float)mv[j];
    }
    __syncthreads();

    const int c4 = (t >> 4) * 4, e4 = (t & 15) * 4;
    float sa[4][4] = {}, ya[4][4] = {};
#pragma unroll 2
    for (int d = 0; d < 64; ++d) {
        float a[4], bb[4], m[4];
        *(float4*)a = *(const float4*)(qT + d * 64 + c4);
        *(float4*)bb = *(const float4*)(Kd + d * 64 + e4);
        *(float4*)m = *(const float4*)(Ms + d * 64 + e4);
#pragma unroll
        for (int i = 0; i < 4; ++i)
#pragma unroll
            for (int j = 0; j < 4; ++j) {
                sa[i][j] = fmaf(a[i], bb[j], sa[i][j]);
                ya[i][j] = fmaf(a[i], m[j], ya[i][j]);
            }
    }
#pragma unroll
    for (int i = 0; i < 4; ++i)
#pragma unroll
        for (int j = 0; j < 4; ++j)
            if (e4 + j > c4 + i) sa[i][j] = 0.0f;
    __syncthreads();
#pragma unroll
    for (int i = 0; i < 4; ++i)
#pragma unroll
        for (int j = 0; j < 4; ++j)
            qT[(e4 + j) * 64 + c4 + i] = sa[i][j];
    __syncthreads();
#pragma unroll 2
    for (int e = 0; e < 64; ++e) {
        float a[4], vv[4];
        *(float4*)a = *(const float4*)(qT + e * 64 + c4);
        *(float4*)vv = *(const float4*)(Vs + e * 64 + e4);
#pragma unroll
        for (int i = 0; i < 4; ++i)
#pragma unroll
            for (int j = 0; j < 4; ++j)
                ya[i][j] = fmaf(a[i], vv[j], ya[i][j]);
    }
#pragma unroll
    for (int i = 0; i < 4; ++i) {
        f16x4 o;
        o[0] = (f16)ya[i][0]; o[1] = (f16)ya[i][1];
        o[2] = (f16)ya[i][2]; o[3] = (f16)ya[i][3];
        *(f16x4*)(y + ((size_t)b * SEQL + ch * 64 + c4 + i) * DM + h * 64 + e4) = o;
    }
}

// ---------------- launch --------------------------------------------------------
extern "C" void kernel_launch(void* const* d_in, const int* in_sizes, int n_in,
                              void* d_out, int out_size, void* d_ws, size_t ws_size,
                              hipStream_t stream)
{
    const float* x      = (const float*)d_in[0];
    const float* norm_w = (const float*)d_in[1];
    const float* w_up   = (const float*)d_in[2];
    const float* w_gate = (const float*)d_in[3];
    const float* w_down = (const float*)d_in[4];
    const float* conv_w = (const float*)d_in[5];
    const float* conv_b = (const float*)d_in[6];
    const float* wq     = (const float*)d_in[7];
    const float* wk     = (const float*)d_in[8];
    const float* wv     = (const float*)d_in[9];
    const float* wo     = (const float*)d_in[10];
    float* out = (float*)d_out;

    const size_t BIG_NEED = 247463936ull;
    const bool big = ws_size >= BIG_NEED;

    if (big) {
        char* p = (char*)d_ws;
        f16* upg = (f16*)p;               p += (size_t)NRALL * 4096 * 2;
        f16* hb  = (f16*)p;               p += (size_t)NRALL * DM * 2;
        char* fmtD   = p;                 p += (size_t)64 * 1024 * 64;
        char* fmtQKV = p;                 p += (size_t)32 * 3072 * 64;
        char* fmtO   = p;                 p += (size_t)32 * 1024 * 64;
        f16* xn = (f16*)p;                p += (size_t)NRALL * DM * 2;
        char* fmtUG  = p;
        f16* G = (f16*)xn;                // overlays xn+fmtUG (dead after up/gate GEMM)
        f16* qkvb = upg;
        f16* yb   = hb;

        rmsnorm_k<<<NRALL, 256, 0, stream>>>(x, norm_w, xn);
        wfmt_all_k<<<640, 256, 0, stream>>>(w_up, w_gate, w_down, wq, wk, wv, wo,
                                            fmtUG, fmtD, fmtQKV, fmtO);

        mg256_k<0><<<16 * 64, 512, 0, stream>>>(xn, DM, fmtUG, upg, 4096, DM, 16, nullptr);
        conv_gate_k<<<NRALL / 16, 256, 0, stream>>>(upg, conv_w, conv_b);
        mg256_k<0><<<4 * 64, 512, 0, stream>>>(upg + 2048, 4096, fmtD, hb, 1024, DI, 4, nullptr);
        mg256_k<1><<<12 * 64, 512, 0, stream>>>(hb, DM, fmtQKV, qkvb, 3072, DM, 12, nullptr);

        gscan_g_k<<<dim3(64, 16, 4), 256, 0, stream>>>(qkvb, G);
        gprefix_k<<<1024, 256, 0, stream>>>(G);
        gscan_y_k<<<dim3(64, 16, 4), 256, 0, stream>>>(qkvb, G, yb);

        mg256_k<2><<<4 * 64, 512, 0, stream>>>(yb, DM, fmtO, out, 1024, DM, 4, x);
    } else {
        // compact per-batch path
        char* p = (char*)d_ws;
        f16* xn = (f16*)p;                p += (size_t)NRALL * DM * 2;
        f16* upg = (f16*)p;               p += (size_t)SEQL * 4096 * 2;
        f16* hb  = (f16*)p;               p += (size_t)SEQL * DM * 2;
        f16* G = (f16*)p;                 p += (size_t)16 * 64 * 4096 * 2;
        char* fmtUG  = p;                 p += (size_t)32 * 4096 * 64;
        char* fmtD   = p;                 p += (size_t)64 * 1024 * 64;
        char* fmtQKV = p;                 p += (size_t)32 * 3072 * 64;
        char* fmtO   = p;
        f16* qkvb = upg;
        f16* yb   = hb;

        rmsnorm_k<<<NRALL, 256, 0, stream>>>(x, norm_w, xn);
        wfmt_all_k<<<640, 256, 0, stream>>>(w_up, w_gate, w_down, wq, wk, wv, wo,
                                            fmtUG, fmtD, fmtQKV, fmtO);

        for (int b = 0; b < 4; ++b) {
            const f16* xnb = xn + (size_t)b * SEQL * DM;
            mg256_k<0><<<16 * 16, 512, 0, stream>>>(xnb, DM, fmtUG, upg, 4096, DM, 16, nullptr);
            conv_gate_k<<<SEQL / 16, 256, 0, stream>>>(upg, conv_w, conv_b);
            mg256_k<0><<<4 * 16, 512, 0, stream>>>(upg + 2048, 4096, fmtD, hb, 1024, DI, 4, nullptr);
            mg256_k<1><<<12 * 16, 512, 0, stream>>>(hb, DM, fmtQKV, qkvb, 3072, DM, 12, nullptr);
            gscan_g_k<<<dim3(64, 16, 1), 256, 0, stream>>>(qkvb, G);
            gprefix_k<<<256, 256, 0, stream>>>(G);
            gscan_y_k<<<dim3(64, 16, 1), 256, 0, stream>>>(qkvb, G, yb);
            mg256_k<2><<<4 * 16, 512, 0, stream>>>(yb, DM, fmtO,
                                                   out + (size_t)b * SEQL * DM, 1024, DM, 4,
                                                   x + (size_t)b * SEQL * DM);
        }
    }
}

// Round 12
// 621.553 us; speedup vs baseline: 1.0009x; 1.0009x over previous
//
#include <hip/hip_runtime.h>
#include <hip/hip_fp16.h>
#include <cstdint>

// Problem constants (B=4, S=4096, D=1024)
#define NRALL 16384
#define DM    1024
#define DI    2048
#define SEQL  4096

typedef _Float16 f16;
typedef _Float16 f16x8 __attribute__((ext_vector_type(8)));
typedef _Float16 f16x4 __attribute__((ext_vector_type(4)));
typedef float    f32x4 __attribute__((ext_vector_type(4)));

__device__ __forceinline__ float phi_f(float t)  { return t > 0.0f ? t + 1.0f : __expf(t); }
__device__ __forceinline__ float silu_f(float t) { return t / (1.0f + __expf(-t)); }

#define GLDS16(g, l)                                                            \
    __builtin_amdgcn_global_load_lds(                                           \
        (const __attribute__((address_space(1))) void*)(g),                     \
        (__attribute__((address_space(3))) void*)(l), 16, 0, 0)

#define FMA4(dst, s, vv)                      \
    dst.x = fmaf((s), (vv).x, dst.x);         \
    dst.y = fmaf((s), (vv).y, dst.y);         \
    dst.z = fmaf((s), (vv).z, dst.z);         \
    dst.w = fmaf((s), (vv).w, dst.w;)

// ---------------- 1. merged prep: rmsnorm rows + weight format ------------------
// blocks [0,16384): rmsnorm row; [16384, 16384+640): wfmt ids.
__device__ __forceinline__ void wfmt_one(const float* __restrict__ W, char* __restrict__ fmt,
                                         int n, int kt, int Nw, int Ntot, int noff)
{
    const int ng = noff + n;
#pragma unroll
    for (int kh = 0; kh < 2; ++kh) {
        char* o = fmt + ((size_t)(kt * 2 + kh) * Ntot + ng) * 64;
#pragma unroll
        for (int c2 = 0; c2 < 4; ++c2) {
            f16x8 p;
#pragma unroll
            for (int j = 0; j < 8; ++j)
                p[j] = (f16)W[(size_t)(kt * 64 + kh * 32 + c2 * 8 + j) * Nw + n];
            *(f16x8*)(o + ((c2 ^ ((ng >> 1) & 3)) << 4)) = p;
        }
    }
}

__global__ __launch_bounds__(256) void prep_k(const float* __restrict__ x,
                                              const float* __restrict__ nw,
                                              f16* __restrict__ xn,
                                              const float* __restrict__ w_up,
                                              const float* __restrict__ w_gate,
                                              const float* __restrict__ w_down,
                                              const float* __restrict__ wq,
                                              const float* __restrict__ wk,
                                              const float* __restrict__ wv,
                                              const float* __restrict__ wo,
                                              char* __restrict__ fmtUG,
                                              char* __restrict__ fmtD,
                                              char* __restrict__ fmtQKV,
                                              char* __restrict__ fmtO)
{
    const int t = threadIdx.x;
    if (blockIdx.x < NRALL) {
        const int r = blockIdx.x;
        const float4 v = *(const float4*)(x + (size_t)r * DM + t * 4);
        float s = v.x * v.x + v.y * v.y + v.z * v.z + v.w * v.w;
#pragma unroll
        for (int m = 1; m < 64; m <<= 1) s += __shfl_xor(s, m);
        __shared__ float ws4[4];
        if ((t & 63) == 0) ws4[t >> 6] = s;
        __syncthreads();
        const float tot = ws4[0] + ws4[1] + ws4[2] + ws4[3];
        const float sc = rsqrtf(tot * (1.0f / DM) + 1e-5f);
        const float4 w = *(const float4*)(nw + t * 4);
        f16x4 o;
        o[0] = (f16)(v.x * sc * w.x); o[1] = (f16)(v.y * sc * w.y);
        o[2] = (f16)(v.z * sc * w.z); o[3] = (f16)(v.w * sc * w.w);
        *(f16x4*)(xn + (size_t)r * DM + t * 4) = o;
        return;
    }
    int id = blockIdx.x - NRALL;
    if (id < 128) { wfmt_one(w_up,   fmtUG,  (id % 8) * 256 + t, id / 8, DI, 4096, 0);    return; }
    id -= 128;
    if (id < 128) { wfmt_one(w_gate, fmtUG,  (id % 8) * 256 + t, id / 8, DI, 4096, 2048); return; }
    id -= 128;
    if (id < 128) { wfmt_one(w_down, fmtD,   (id % 4) * 256 + t, id / 4, DM, 1024, 0);    return; }
    id -= 128;
    if (id < 64)  { wfmt_one(wq,     fmtQKV, (id % 4) * 256 + t, id / 4, DM, 3072, 0);    return; }
    id -= 64;
    if (id < 64)  { wfmt_one(wk,     fmtQKV, (id % 4) * 256 + t, id / 4, DM, 3072, 1024); return; }
    id -= 64;
    if (id < 64)  { wfmt_one(wv,     fmtQKV, (id % 4) * 256 + t, id / 4, DM, 3072, 2048); return; }
    id -= 64;
    wfmt_one(wo, fmtO, (id % 4) * 256 + t, id / 4, DM, 1024, 0);
}

// ---------------- 2. 256x256 MFMA GEMM, 16 waves (4m x 4n), 8-phase -------------
// 1024 thr = 16 waves, each owns 64x64 -> acc 4x4 f32x4 = 64 VGPR -> <=128 VGPR
// -> 4 waves/SIMD resident: within each lockstep phase the SIMD interleaves 4
// waves' ds_reads/glds with MFMAs (TLP hides LDS latency; pipes overlap).
// LDS 128KB: 8 slots of 16KB = {A,B} x 2buf x 2 K32-halves.
// Phase P (p=buf, ks=K32-half, mh=row-half): reads mh0: af[0..1]+bf[0..3] (6),
// mh1: af[2..3] (2, bf reused in regs); stage 1 slot (1 glds/thread);
// vmcnt(3) -> barrier -> lgkm(0) -> setprio(1) 8 MFMA setprio(0).
// Hazards (audited): WAR: every stage targets a slot whose last read-issue was
// exactly 2 phases back (reads drained at lgkm0 after barrier_{P-2} < all waves'
// barrier_{P-1} < stage issue). RAW: vmcnt(3)@P certifies stages <=P-3 at
// barrier_P; every read is >=5 phases after its stage. Prologue: 6 glds,
// vmcnt(4) certifies (0,k0); chain certifies the rest phase by phase.
#define PH(p, ks, mh, STAGE_STMT)                                                 \
    {                                                                             \
        if ((mh) == 0) {                                                          \
            _Pragma("unroll")                                                     \
            for (int q = 0; q < 2; ++q) {                                         \
                const int row = wm * 64 + q * 16 + lr16;                          \
                af[q] = *(const f16x8*)(ldsb + (p) * 32768 + (ks) * 16384         \
                        + row * 64 + ((kb ^ ((row >> 1) & 3)) << 4));             \
            }                                                                     \
            _Pragma("unroll")                                                     \
            for (int q = 0; q < 4; ++q) {                                         \
                const int n = wn * 64 + q * 16 + lr16;                            \
                bf[q] = *(const f16x8*)(ldsb + 65536 + (p) * 32768 + (ks) * 16384 \
                        + n * 64 + ((kb ^ ((n >> 1) & 3)) << 4));                 \
            }                                                                     \
        } else {                                                                  \
            _Pragma("unroll")                                                     \
            for (int q = 0; q < 2; ++q) {                                         \
                const int row = wm * 64 + (q + 2) * 16 + lr16;                    \
                af[2 + q] = *(const f16x8*)(ldsb + (p) * 32768 + (ks) * 16384     \
                            + row * 64 + ((kb ^ ((row >> 1) & 3)) << 4));         \
            }                                                                     \
        }                                                                         \
        STAGE_STMT;                                                               \
        asm volatile("s_waitcnt vmcnt(3)" ::: "memory");                          \
        __builtin_amdgcn_sched_barrier(0);                                        \
        __builtin_amdgcn_s_barrier();                                             \
        asm volatile("s_waitcnt lgkmcnt(0)" ::: "memory");                        \
        __builtin_amdgcn_sched_barrier(0);                                        \
        __builtin_amdgcn_s_setprio(1);                                            \
        _Pragma("unroll")                                                         \
        for (int q = 0; q < 2; ++q) {                                             \
            acc[(mh) * 2 + q][0] = __builtin_amdgcn_mfma_f32_16x16x32_f16(        \
                af[(mh) * 2 + q], bf[0], acc[(mh) * 2 + q][0], 0, 0, 0);          \
            acc[(mh) * 2 + q][1] = __builtin_amdgcn_mfma_f32_16x16x32_f16(        \
                af[(mh) * 2 + q], bf[1], acc[(mh) * 2 + q][1], 0, 0, 0);          \
            acc[(mh) * 2 + q][2] = __builtin_amdgcn_mfma_f32_16x16x32_f16(        \
                af[(mh) * 2 + q], bf[2], acc[(mh) * 2 + q][2], 0, 0, 0);          \
            acc[(mh) * 2 + q][3] = __builtin_amdgcn_mfma_f32_16x16x32_f16(        \
                af[(mh) * 2 + q], bf[3], acc[(mh) * 2 + q][3], 0, 0, 0);          \
        }                                                                         \
        __builtin_amdgcn_s_setprio(0);                                            \
        __builtin_amdgcn_sched_barrier(0);                                        \
    }

template <int EPI>
__global__ __launch_bounds__(1024) void mg256_k(const f16* __restrict__ A, int lda,
                                                const char* __restrict__ fmt,
                                                void* __restrict__ Cv,
                                                int N, int K, int gx,
                                                const float* __restrict__ addx)
{
    __shared__ __align__(16) char ldsb[131072];

    const int t = threadIdx.x;
    int wid = blockIdx.x;
    { const int cpx = gridDim.x >> 3; wid = (wid & 7) * cpx + (wid >> 3); }  // XCD swizzle
    const int bx = wid % gx, by = wid / gx;
    const int bm = by * 256, bn = bx * 256;
    const int lane = t & 63, wv = t >> 6;       // wave 0..15
    const int wm = wv >> 2, wn = wv & 3;        // 4x4 wave grid
    const int kb = lane >> 4, lr16 = lane & 15;
    const int NT = K >> 6;

    f32x4 acc[4][4];
#pragma unroll
    for (int i = 0; i < 4; ++i)
#pragma unroll
        for (int j = 0; j < 4; ++j) acc[i][j] = (f32x4)0.0f;

    // per-thread staging bases (1 glds per stage call)
    const int arow = t >> 2;
    const int ac2 = (t & 3) ^ ((arow >> 1) & 3);
    const f16* Abase = A + (size_t)(bm + arow) * lda + ac2 * 8;
    const char* Bbase = fmt + (size_t)bn * 64 + (size_t)t * 16;
    const size_t BKstep = (size_t)N * 64;
    char* ldsT = ldsb + t * 16;

    auto STAGE_A = [&](int p, int kh, int kt) {
        GLDS16(Abase + kt * 64 + kh * 32, ldsT + p * 32768 + kh * 16384);
    };
    auto STAGE_B = [&](int p, int kh, int kt) {
        GLDS16(Bbase + (size_t)(kt * 2 + kh) * BKstep, ldsT + 65536 + p * 32768 + kh * 16384);
    };

    f16x8 af[4], bf[4];

    // prologue: B00,A00,B01,A01 <- t0; B10,A10 <- t1; vmcnt(4) -> (0,k0) landed
    const int T1 = NT > 1 ? 1 : 0;
    STAGE_B(0, 0, 0); STAGE_A(0, 0, 0);
    STAGE_B(0, 1, 0); STAGE_A(0, 1, 0);
    STAGE_B(1, 0, T1); STAGE_A(1, 0, T1);
    asm volatile("s_waitcnt vmcnt(4)" ::: "memory");
    __builtin_amdgcn_s_barrier();
    __builtin_amdgcn_sched_barrier(0);

    const int NI = NT >> 1;
    for (int i = 0; i < NI; ++i) {
        const int tA = 2 * i + 1 < NT ? 2 * i + 1 : NT - 1;
        const int tB = 2 * i + 2 < NT ? 2 * i + 2 : NT - 1;
        const int tC = 2 * i + 3 < NT ? 2 * i + 3 : NT - 1;
        PH(0, 0, 0, STAGE_B(1, 1, tA))
        PH(0, 0, 1, STAGE_A(1, 1, tA))
        PH(0, 1, 0, STAGE_B(0, 0, tB))
        PH(0, 1, 1, STAGE_A(0, 0, tB))
        PH(1, 0, 0, STAGE_B(0, 1, tB))
        PH(1, 0, 1, STAGE_A(0, 1, tB))
        PH(1, 1, 0, STAGE_B(1, 0, tC))
        PH(1, 1, 1, STAGE_A(1, 0, tC))
    }
    asm volatile("s_waitcnt vmcnt(0)" ::: "memory");  // drain DMA before LDS freed

    // ---- epilogue: C frag col=lane&15, row=(lane>>4)*4+r
#pragma unroll
    for (int fm = 0; fm < 4; ++fm) {
        const int row0 = bm + wm * 64 + fm * 16 + kb * 4;
#pragma unroll
        for (int fn = 0; fn < 4; ++fn) {
            const int col = bn + wn * 64 + fn * 16 + lr16;
#pragma unroll
            for (int r = 0; r < 4; ++r) {
                float o = acc[fm][fn][r];
                if (EPI == 1) {
                    if (col < DM) o = phi_f(o) * 0.125f;
                    else if (col < 2 * DM) o = phi_f(o);
                }
                if (EPI == 2) {
                    ((float*)Cv)[(size_t)(row0 + r) * N + col] =
                        o + addx[(size_t)(row0 + r) * N + col];
                } else {
                    ((f16*)Cv)[(size_t)(row0 + r) * N + col] = (f16)o;
                }
            }
        }
    }
}

// ---------------- 3. causal dwconv + silu + gate, rolling window ----------------
__global__ __launch_bounds__(256) void conv_gate_k(f16* __restrict__ upg,
                                                   const float* __restrict__ cw,
                                                   const float* __restrict__ cb)
{
    const int r0 = blockIdx.x * 16;
    const int c = threadIdx.x * 8;
    float bias[8];
    {
        const float4 b0 = *(const float4*)(cb + c);
        const float4 b1 = *(const float4*)(cb + c + 4);
        bias[0] = b0.x; bias[1] = b0.y; bias[2] = b0.z; bias[3] = b0.w;
        bias[4] = b1.x; bias[5] = b1.y; bias[6] = b1.z; bias[7] = b1.w;
    }
    float tap[8][4];
#pragma unroll
    for (int j = 0; j < 8; ++j)
        *(float4*)tap[j] = *(const float4*)(cw + (size_t)(c + j) * 4);

    const bool lead = (r0 & (SEQL - 1)) == 0;
    f16x8 w0, w1, w2;
    if (lead) {
        w0 = (f16x8)(f16)0; w1 = (f16x8)(f16)0; w2 = (f16x8)(f16)0;
    } else {
        w0 = *(const f16x8*)(upg + (size_t)(r0 - 3) * 4096 + c);
        w1 = *(const f16x8*)(upg + (size_t)(r0 - 2) * 4096 + c);
        w2 = *(const f16x8*)(upg + (size_t)(r0 - 1) * 4096 + c);
    }
#pragma unroll 4
    for (int i = 0; i < 16; ++i) {
        const size_t row = (size_t)(r0 + i);
        const f16x8 w3 = *(const f16x8*)(upg + row * 4096 + c);
        const f16x8 g  = *(const f16x8*)(upg + row * 4096 + 2048 + c);
        f16x8 o;
#pragma unroll
        for (int j = 0; j < 8; ++j) {
            float a = bias[j];
            a = fmaf((float)w0[j], tap[j][0], a);
            a = fmaf((float)w1[j], tap[j][1], a);
            a = fmaf((float)w2[j], tap[j][2], a);
            a = fmaf((float)w3[j], tap[j][3], a);
            o[j] = (f16)(silu_f((float)g[j]) * silu_f(a));
        }
        *(f16x8*)(upg + row * 4096 + 2048 + c) = o;
        w0 = w1; w1 = w2; w2 = w3;
    }
}

// ---------------- 4a. per-chunk outer products: G[b][h][ch] = K^T V (f16 out) ---
__global__ __launch_bounds__(256) void gscan_g_k(const f16* __restrict__ qkv,
                                                 f16* __restrict__ G)
{
    __shared__ float Ks[4096];
    __shared__ float Vs[4096];
    const int t = threadIdx.x, ch = blockIdx.x, h = blockIdx.y, b = blockIdx.z;
    const int r = t >> 2, c16 = (t & 3) * 16;
    const f16* kp = qkv + ((size_t)b * SEQL + ch * 64 + r) * 3072 + DM + h * 64 + c16;
#pragma unroll
    for (int i = 0; i < 2; ++i) {
        const f16x8 kv = *(const f16x8*)(kp + 8 * i);
        const f16x8 vv = *(const f16x8*)(kp + DM + 8 * i);
#pragma unroll
        for (int j = 0; j < 8; ++j) {
            Ks[r * 64 + c16 + 8 * i + j] = (float)kv[j];
            Vs[r * 64 + c16 + 8 * i + j] = (float)vv[j];
        }
    }
    __syncthreads();
    const int d4 = (t >> 4) * 4, e4 = (t & 15) * 4;
    float4 ag[4] = {};
#pragma unroll 4
    for (int c = 0; c < 64; ++c) {
        float ka[4];
        *(float4*)ka = *(const float4*)(Ks + c * 64 + d4);
        const float4 va = *(const float4*)(Vs + c * 64 + e4);
        ag[0].x = fmaf(ka[0], va.x, ag[0].x); ag[0].y = fmaf(ka[0], va.y, ag[0].y);
        ag[0].z = fmaf(ka[0], va.z, ag[0].z); ag[0].w = fmaf(ka[0], va.w, ag[0].w);
        ag[1].x = fmaf(ka[1], va.x, ag[1].x); ag[1].y = fmaf(ka[1], va.y, ag[1].y);
        ag[1].z = fmaf(ka[1], va.z, ag[1].z); ag[1].w = fmaf(ka[1], va.w, ag[1].w);
        ag[2].x = fmaf(ka[2], va.x, ag[2].x); ag[2].y = fmaf(ka[2], va.y, ag[2].y);
        ag[2].z = fmaf(ka[2], va.z, ag[2].z); ag[2].w = fmaf(ka[2], va.w, ag[2].w);
        ag[3].x = fmaf(ka[3], va.x, ag[3].x); ag[3].y = fmaf(ka[3], va.y, ag[3].y);
        ag[3].z = fmaf(ka[3], va.z, ag[3].z); ag[3].w = fmaf(ka[3], va.w, ag[3].w);
    }
    f16* go = G + (((size_t)b * 16 + h) * 64 + ch) * 4096 + d4 * 64 + e4;
#pragma unroll
    for (int i = 0; i < 4; ++i) {
        f16x4 o;
        o[0] = (f16)ag[i].x; o[1] = (f16)ag[i].y;
        o[2] = (f16)ag[i].z; o[3] = (f16)ag[i].w;
        *(f16x4*)(go + i * 64) = o;
    }
}

// ---------------- 4b. in-place exclusive prefix over chunks (f16, fp32 carry) ---
__global__ __launch_bounds__(256) void gprefix_k(f16* __restrict__ G)
{
    const int bh = blockIdx.x >> 4, sl = blockIdx.x & 15;
    const int idx = sl * 256 + threadIdx.x;
    float run = 0.0f;
    f16* p = G + (size_t)bh * 64 * 4096 + idx;
#pragma unroll 4
    for (int ch = 0; ch < 64; ++ch) {
        const float g = (float)*p;
        *p = (f16)run;
        run += g;
        p += 4096;
    }
}

// ---------------- 4c. per-chunk read: y = q*M_excl + tril(q k^T) v --------------
__global__ __launch_bounds__(256) void gscan_y_k(const f16* __restrict__ qkv,
                                                 const f16* __restrict__ G,
                                                 f16* __restrict__ y)
{
    __shared__ float qT[4096];   // qT[d][c]; later scT[e][c]
    __shared__ float Kd[4096];   // Kd[d][e] = K[e][d]
    __shared__ float Vs[4096];
    __shared__ float Ms[4096];
    const int t = threadIdx.x, ch = blockIdx.x, h = blockIdx.y, b = blockIdx.z;
    const int r = t >> 2, c16 = (t & 3) * 16;
    const f16* qp = qkv + ((size_t)b * SEQL + ch * 64 + r) * 3072 + h * 64 + c16;
#pragma unroll
    for (int i = 0; i < 2; ++i) {
        const f16x8 qv = *(const f16x8*)(qp + 8 * i);
        const f16x8 kv = *(const f16x8*)(qp + DM + 8 * i);
        const f16x8 vv = *(const f16x8*)(qp + 2 * DM + 8 * i);
#pragma unroll
        for (int j = 0; j < 8; ++j) {
            qT[(c16 + 8 * i + j) * 64 + r] = (float)qv[j];
            Kd[(c16 + 8 * i + j) * 64 + r] = (float)kv[j];
            Vs[r * 64 + c16 + 8 * i + j] = (float)vv[j];
        }
    }
    const f16* mg = G + (((size_t)b * 16 + h) * 64 + ch) * 4096;
#pragma unroll
    for (int i = 0; i < 2; ++i) {
        const f16x8 mv = *(const f16x8*)(mg + t * 16 + 8 * i);
#pragma unroll
        for (int j = 0; j < 8; ++j) Ms[t * 16 + 8 * i + j] = (float)mv[j];
    }
    __syncthreads();

    const int c4 = (t >> 4) * 4, e4 = (t & 15) * 4;
    float sa[4][4] = {}, ya[4][4] = {};
#pragma unroll 2
    for (int d = 0; d < 64; ++d) {
        float a[4], bb[4], m[4];
        *(float4*)a = *(const float4*)(qT + d * 64 + c4);
        *(float4*)bb = *(const float4*)(Kd + d * 64 + e4);
        *(float4*)m = *(const float4*)(Ms + d * 64 + e4);
#pragma unroll
        for (int i = 0; i < 4; ++i)
#pragma unroll
            for (int j = 0; j < 4; ++j) {
                sa[i][j] = fmaf(a[i], bb[j], sa[i][j]);
                ya[i][j] = fmaf(a[i], m[j], ya[i][j]);
            }
    }
#pragma unroll
    for (int i = 0; i < 4; ++i)
#pragma unroll
        for (int j = 0; j < 4; ++j)
            if (e4 + j > c4 + i) sa[i][j] = 0.0f;
    __syncthreads();
#pragma unroll
    for (int i = 0; i < 4; ++i)
#pragma unroll
        for (int j = 0; j < 4; ++j)
            qT[(e4 + j) * 64 + c4 + i] = sa[i][j];
    __syncthreads();
#pragma unroll 2
    for (int e = 0; e < 64; ++e) {
        float a[4], vv[4];
        *(float4*)a = *(const float4*)(qT + e * 64 + c4);
        *(float4*)vv = *(const float4*)(Vs + e * 64 + e4);
#pragma unroll
        for (int i = 0; i < 4; ++i)
#pragma unroll
            for (int j = 0; j < 4; ++j)
                ya[i][j] = fmaf(a[i], vv[j], ya[i][j]);
    }
#pragma unroll
    for (int i = 0; i < 4; ++i) {
        f16x4 o;
        o[0] = (f16)ya[i][0]; o[1] = (f16)ya[i][1];
        o[2] = (f16)ya[i][2]; o[3] = (f16)ya[i][3];
        *(f16x4*)(y + ((size_t)b * SEQL + ch * 64 + c4 + i) * DM + h * 64 + e4) = o;
    }
}

// ---------------- launch --------------------------------------------------------
extern "C" void kernel_launch(void* const* d_in, const int* in_sizes, int n_in,
                              void* d_out, int out_size, void* d_ws, size_t ws_size,
                              hipStream_t stream)
{
    const float* x      = (const float*)d_in[0];
    const float* norm_w = (const float*)d_in[1];
    const float* w_up   = (const float*)d_in[2];
    const float* w_gate = (const float*)d_in[3];
    const float* w_down = (const float*)d_in[4];
    const float* conv_w = (const float*)d_in[5];
    const float* conv_b = (const float*)d_in[6];
    const float* wq     = (const float*)d_in[7];
    const float* wk     = (const float*)d_in[8];
    const float* wv     = (const float*)d_in[9];
    const float* wo     = (const float*)d_in[10];
    float* out = (float*)d_out;

    const size_t BIG_NEED = 247463936ull;
    const bool big = ws_size >= BIG_NEED;

    if (big) {
        char* p = (char*)d_ws;
        f16* upg = (f16*)p;               p += (size_t)NRALL * 4096 * 2;
        f16* hb  = (f16*)p;               p += (size_t)NRALL * DM * 2;
        char* fmtD   = p;                 p += (size_t)64 * 1024 * 64;
        char* fmtQKV = p;                 p += (size_t)32 * 3072 * 64;
        char* fmtO   = p;                 p += (size_t)32 * 1024 * 64;
        f16* xn = (f16*)p;                p += (size_t)NRALL * DM * 2;
        char* fmtUG  = p;
        f16* G = (f16*)xn;                // overlays xn+fmtUG (dead after up/gate GEMM)
        f16* qkvb = upg;
        f16* yb   = hb;

        prep_k<<<NRALL + 640, 256, 0, stream>>>(x, norm_w, xn, w_up, w_gate, w_down,
                                                wq, wk, wv, wo, fmtUG, fmtD, fmtQKV, fmtO);

        mg256_k<0><<<16 * 64, 1024, 0, stream>>>(xn, DM, fmtUG, upg, 4096, DM, 16, nullptr);
        conv_gate_k<<<NRALL / 16, 256, 0, stream>>>(upg, conv_w, conv_b);
        mg256_k<0><<<4 * 64, 1024, 0, stream>>>(upg + 2048, 4096, fmtD, hb, 1024, DI, 4, nullptr);
        mg256_k<1><<<12 * 64, 1024, 0, stream>>>(hb, DM, fmtQKV, qkvb, 3072, DM, 12, nullptr);

        gscan_g_k<<<dim3(64, 16, 4), 256, 0, stream>>>(qkvb, G);
        gprefix_k<<<1024, 256, 0, stream>>>(G);
        gscan_y_k<<<dim3(64, 16, 4), 256, 0, stream>>>(qkvb, G, yb);

        mg256_k<2><<<4 * 64, 1024, 0, stream>>>(yb, DM, fmtO, out, 1024, DM, 4, x);
    } else {
        // compact per-batch path
        char* p = (char*)d_ws;
        f16* xn = (f16*)p;                p += (size_t)NRALL * DM * 2;
        f16* upg = (f16*)p;               p += (size_t)SEQL * 4096 * 2;
        f16* hb  = (f16*)p;               p += (size_t)SEQL * DM * 2;
        f16* G = (f16*)p;                 p += (size_t)16 * 64 * 4096 * 2;
        char* fmtUG  = p;                 p += (size_t)32 * 4096 * 64;
        char* fmtD   = p;                 p += (size_t)64 * 1024 * 64;
        char* fmtQKV = p;                 p += (size_t)32 * 3072 * 64;
        char* fmtO   = p;
        f16* qkvb = upg;
        f16* yb   = hb;

        prep_k<<<NRALL + 640, 256, 0, stream>>>(x, norm_w, xn, w_up, w_gate, w_down,
                                                wq, wk, wv, wo, fmtUG, fmtD, fmtQKV, fmtO);

        for (int b = 0; b < 4; ++b) {
            const f16* xnb = xn + (size_t)b * SEQL * DM;
            mg256_k<0><<<16 * 16, 1024, 0, stream>>>(xnb, DM, fmtUG, upg, 4096, DM, 16, nullptr);
            conv_gate_k<<<SEQL / 16, 256, 0, stream>>>(upg, conv_w, conv_b);
            mg256_k<0><<<4 * 16, 1024, 0, stream>>>(upg + 2048, 4096, fmtD, hb, 1024, DI, 4, nullptr);
            mg256_k<1><<<12 * 16, 1024, 0, stream>>>(hb, DM, fmtQKV, qkvb, 3072, DM, 12, nullptr);
            gscan_g_k<<<dim3(64, 16, 1), 256, 0, stream>>>(qkvb, G);
            gprefix_k<<<256, 256, 0, stream>>>(G);
            gscan_y_k<<<dim3(64, 16, 1), 256, 0, stream>>>(qkvb, G, yb);
            mg256_k<2><<<4 * 16, 1024, 0, stream>>>(yb, DM, fmtO,
                                                    out + (size_t)b * SEQL * DM, 1024, DM, 4,
                                                    x + (size_t)b * SEQL * DM);
        }
    }
}

// Round 13
// 533.999 us; speedup vs baseline: 1.1650x; 1.1640x over previous
//
#include <hip/hip_runtime.h>
#include <hip/hip_fp16.h>
#include <cstdint>

// Problem constants (B=4, S=4096, D=1024)
#define NRALL 16384
#define DM    1024
#define DI    2048
#define SEQL  4096

typedef _Float16 f16;
typedef _Float16 f16x8 __attribute__((ext_vector_type(8)));
typedef _Float16 f16x4 __attribute__((ext_vector_type(4)));
typedef _Float16 f16x2 __attribute__((ext_vector_type(2)));
typedef float    f32x4 __attribute__((ext_vector_type(4)));

__device__ __forceinline__ float phi_f(float t)  { return t > 0.0f ? t + 1.0f : __expf(t); }
__device__ __forceinline__ float silu_f(float t) { return t / (1.0f + __expf(-t)); }

#define GLDS16(g, l)                                                            \
    __builtin_amdgcn_global_load_lds(                                           \
        (const __attribute__((address_space(1))) void*)(g),                     \
        (__attribute__((address_space(3))) void*)(l), 16, 0, 0)

// ---------------- 1. merged prep: rmsnorm rows + weight format ------------------
__device__ __forceinline__ void wfmt_one(const float* __restrict__ W, char* __restrict__ fmt,
                                         int n, int kt, int Nw, int Ntot, int noff)
{
    const int ng = noff + n;
#pragma unroll
    for (int kh = 0; kh < 2; ++kh) {
        char* o = fmt + ((size_t)(kt * 2 + kh) * Ntot + ng) * 64;
#pragma unroll
        for (int c2 = 0; c2 < 4; ++c2) {
            f16x8 p;
#pragma unroll
            for (int j = 0; j < 8; ++j)
                p[j] = (f16)W[(size_t)(kt * 64 + kh * 32 + c2 * 8 + j) * Nw + n];
            *(f16x8*)(o + ((c2 ^ ((ng >> 1) & 3)) << 4)) = p;
        }
    }
}

__global__ __launch_bounds__(256) void prep_k(const float* __restrict__ x,
                                              const float* __restrict__ nw,
                                              f16* __restrict__ xn,
                                              const float* __restrict__ w_up,
                                              const float* __restrict__ w_gate,
                                              const float* __restrict__ w_down,
                                              const float* __restrict__ wq,
                                              const float* __restrict__ wk,
                                              const float* __restrict__ wv,
                                              const float* __restrict__ wo,
                                              char* __restrict__ fmtUG,
                                              char* __restrict__ fmtD,
                                              char* __restrict__ fmtQKV,
                                              char* __restrict__ fmtO)
{
    const int t = threadIdx.x;
    if (blockIdx.x < NRALL) {
        const int r = blockIdx.x;
        const float4 v = *(const float4*)(x + (size_t)r * DM + t * 4);
        float s = v.x * v.x + v.y * v.y + v.z * v.z + v.w * v.w;
#pragma unroll
        for (int m = 1; m < 64; m <<= 1) s += __shfl_xor(s, m);
        __shared__ float ws4[4];
        if ((t & 63) == 0) ws4[t >> 6] = s;
        __syncthreads();
        const float tot = ws4[0] + ws4[1] + ws4[2] + ws4[3];
        const float sc = rsqrtf(tot * (1.0f / DM) + 1e-5f);
        const float4 w = *(const float4*)(nw + t * 4);
        f16x4 o;
        o[0] = (f16)(v.x * sc * w.x); o[1] = (f16)(v.y * sc * w.y);
        o[2] = (f16)(v.z * sc * w.z); o[3] = (f16)(v.w * sc * w.w);
        *(f16x4*)(xn + (size_t)r * DM + t * 4) = o;
        return;
    }
    int id = blockIdx.x - NRALL;
    if (id < 128) { wfmt_one(w_up,   fmtUG,  (id % 8) * 256 + t, id / 8, DI, 4096, 0);    return; }
    id -= 128;
    if (id < 128) { wfmt_one(w_gate, fmtUG,  (id % 8) * 256 + t, id / 8, DI, 4096, 2048); return; }
    id -= 128;
    if (id < 128) { wfmt_one(w_down, fmtD,   (id % 4) * 256 + t, id / 4, DM, 1024, 0);    return; }
    id -= 128;
    if (id < 64)  { wfmt_one(wq,     fmtQKV, (id % 4) * 256 + t, id / 4, DM, 3072, 0);    return; }
    id -= 64;
    if (id < 64)  { wfmt_one(wk,     fmtQKV, (id % 4) * 256 + t, id / 4, DM, 3072, 1024); return; }
    id -= 64;
    if (id < 64)  { wfmt_one(wv,     fmtQKV, (id % 4) * 256 + t, id / 4, DM, 3072, 2048); return; }
    id -= 64;
    wfmt_one(wo, fmtO, (id % 4) * 256 + t, id / 4, DM, 1024, 0);
}

// ---------------- 2. 256x256 MFMA GEMM, 16 waves (4m x 4n), 8-phase -------------
// (unchanged from round 12 — 6 schedule variants all 41-47% MfmaUtil; parked)
#define PH(p, ks, mh, STAGE_STMT)                                                 \
    {                                                                             \
        if ((mh) == 0) {                                                          \
            _Pragma("unroll")                                                     \
            for (int q = 0; q < 2; ++q) {                                         \
                const int row = wm * 64 + q * 16 + lr16;                          \
                af[q] = *(const f16x8*)(ldsb + (p) * 32768 + (ks) * 16384         \
                        + row * 64 + ((kb ^ ((row >> 1) & 3)) << 4));             \
            }                                                                     \
            _Pragma("unroll")                                                     \
            for (int q = 0; q < 4; ++q) {                                         \
                const int n = wn * 64 + q * 16 + lr16;                            \
                bf[q] = *(const f16x8*)(ldsb + 65536 + (p) * 32768 + (ks) * 16384 \
                        + n * 64 + ((kb ^ ((n >> 1) & 3)) << 4));                 \
            }                                                                     \
        } else {                                                                  \
            _Pragma("unroll")                                                     \
            for (int q = 0; q < 2; ++q) {                                         \
                const int row = wm * 64 + (q + 2) * 16 + lr16;                    \
                af[2 + q] = *(const f16x8*)(ldsb + (p) * 32768 + (ks) * 16384     \
                            + row * 64 + ((kb ^ ((row >> 1) & 3)) << 4));         \
            }                                                                     \
        }                                                                         \
        STAGE_STMT;                                                               \
        asm volatile("s_waitcnt vmcnt(3)" ::: "memory");                          \
        __builtin_amdgcn_sched_barrier(0);                                        \
        __builtin_amdgcn_s_barrier();                                             \
        asm volatile("s_waitcnt lgkmcnt(0)" ::: "memory");                        \
        __builtin_amdgcn_sched_barrier(0);                                        \
        __builtin_amdgcn_s_setprio(1);                                            \
        _Pragma("unroll")                                                         \
        for (int q = 0; q < 2; ++q) {                                             \
            acc[(mh) * 2 + q][0] = __builtin_amdgcn_mfma_f32_16x16x32_f16(        \
                af[(mh) * 2 + q], bf[0], acc[(mh) * 2 + q][0], 0, 0, 0);          \
            acc[(mh) * 2 + q][1] = __builtin_amdgcn_mfma_f32_16x16x32_f16(        \
                af[(mh) * 2 + q], bf[1], acc[(mh) * 2 + q][1], 0, 0, 0);          \
            acc[(mh) * 2 + q][2] = __builtin_amdgcn_mfma_f32_16x16x32_f16(        \
                af[(mh) * 2 + q], bf[2], acc[(mh) * 2 + q][2], 0, 0, 0);          \
            acc[(mh) * 2 + q][3] = __builtin_amdgcn_mfma_f32_16x16x32_f16(        \
                af[(mh) * 2 + q], bf[3], acc[(mh) * 2 + q][3], 0, 0, 0);          \
        }                                                                         \
        __builtin_amdgcn_s_setprio(0);                                            \
        __builtin_amdgcn_sched_barrier(0);                                        \
    }

template <int EPI>
__global__ __launch_bounds__(1024) void mg256_k(const f16* __restrict__ A, int lda,
                                                const char* __restrict__ fmt,
                                                void* __restrict__ Cv,
                                                int N, int K, int gx,
                                                const float* __restrict__ addx)
{
    __shared__ __align__(16) char ldsb[131072];

    const int t = threadIdx.x;
    int wid = blockIdx.x;
    { const int cpx = gridDim.x >> 3; wid = (wid & 7) * cpx + (wid >> 3); }  // XCD swizzle
    const int bx = wid % gx, by = wid / gx;
    const int bm = by * 256, bn = bx * 256;
    const int lane = t & 63, wv = t >> 6;
    const int wm = wv >> 2, wn = wv & 3;
    const int kb = lane >> 4, lr16 = lane & 15;
    const int NT = K >> 6;

    f32x4 acc[4][4];
#pragma unroll
    for (int i = 0; i < 4; ++i)
#pragma unroll
        for (int j = 0; j < 4; ++j) acc[i][j] = (f32x4)0.0f;

    const int arow = t >> 2;
    const int ac2 = (t & 3) ^ ((arow >> 1) & 3);
    const f16* Abase = A + (size_t)(bm + arow) * lda + ac2 * 8;
    const char* Bbase = fmt + (size_t)bn * 64 + (size_t)t * 16;
    const size_t BKstep = (size_t)N * 64;
    char* ldsT = ldsb + t * 16;

    auto STAGE_A = [&](int p, int kh, int kt) {
        GLDS16(Abase + kt * 64 + kh * 32, ldsT + p * 32768 + kh * 16384);
    };
    auto STAGE_B = [&](int p, int kh, int kt) {
        GLDS16(Bbase + (size_t)(kt * 2 + kh) * BKstep, ldsT + 65536 + p * 32768 + kh * 16384);
    };

    f16x8 af[4], bf[4];

    const int T1 = NT > 1 ? 1 : 0;
    STAGE_B(0, 0, 0); STAGE_A(0, 0, 0);
    STAGE_B(0, 1, 0); STAGE_A(0, 1, 0);
    STAGE_B(1, 0, T1); STAGE_A(1, 0, T1);
    asm volatile("s_waitcnt vmcnt(4)" ::: "memory");
    __builtin_amdgcn_s_barrier();
    __builtin_amdgcn_sched_barrier(0);

    const int NI = NT >> 1;
    for (int i = 0; i < NI; ++i) {
        const int tA = 2 * i + 1 < NT ? 2 * i + 1 : NT - 1;
        const int tB = 2 * i + 2 < NT ? 2 * i + 2 : NT - 1;
        const int tC = 2 * i + 3 < NT ? 2 * i + 3 : NT - 1;
        PH(0, 0, 0, STAGE_B(1, 1, tA))
        PH(0, 0, 1, STAGE_A(1, 1, tA))
        PH(0, 1, 0, STAGE_B(0, 0, tB))
        PH(0, 1, 1, STAGE_A(0, 0, tB))
        PH(1, 0, 0, STAGE_B(0, 1, tB))
        PH(1, 0, 1, STAGE_A(0, 1, tB))
        PH(1, 1, 0, STAGE_B(1, 0, tC))
        PH(1, 1, 1, STAGE_A(1, 0, tC))
    }
    asm volatile("s_waitcnt vmcnt(0)" ::: "memory");

#pragma unroll
    for (int fm = 0; fm < 4; ++fm) {
        const int row0 = bm + wm * 64 + fm * 16 + kb * 4;
#pragma unroll
        for (int fn = 0; fn < 4; ++fn) {
            const int col = bn + wn * 64 + fn * 16 + lr16;
#pragma unroll
            for (int r = 0; r < 4; ++r) {
                float o = acc[fm][fn][r];
                if (EPI == 1) {
                    if (col < DM) o = phi_f(o) * 0.125f;
                    else if (col < 2 * DM) o = phi_f(o);
                }
                if (EPI == 2) {
                    ((float*)Cv)[(size_t)(row0 + r) * N + col] =
                        o + addx[(size_t)(row0 + r) * N + col];
                } else {
                    ((f16*)Cv)[(size_t)(row0 + r) * N + col] = (f16)o;
                }
            }
        }
    }
}

// ---------------- 3. causal dwconv + silu + gate, rolling window ----------------
__global__ __launch_bounds__(256) void conv_gate_k(f16* __restrict__ upg,
                                                   const float* __restrict__ cw,
                                                   const float* __restrict__ cb)
{
    const int r0 = blockIdx.x * 16;
    const int c = threadIdx.x * 8;
    float bias[8];
    {
        const float4 b0 = *(const float4*)(cb + c);
        const float4 b1 = *(const float4*)(cb + c + 4);
        bias[0] = b0.x; bias[1] = b0.y; bias[2] = b0.z; bias[3] = b0.w;
        bias[4] = b1.x; bias[5] = b1.y; bias[6] = b1.z; bias[7] = b1.w;
    }
    float tap[8][4];
#pragma unroll
    for (int j = 0; j < 8; ++j)
        *(float4*)tap[j] = *(const float4*)(cw + (size_t)(c + j) * 4);

    const bool lead = (r0 & (SEQL - 1)) == 0;
    f16x8 w0, w1, w2;
    if (lead) {
        w0 = (f16x8)(f16)0; w1 = (f16x8)(f16)0; w2 = (f16x8)(f16)0;
    } else {
        w0 = *(const f16x8*)(upg + (size_t)(r0 - 3) * 4096 + c);
        w1 = *(const f16x8*)(upg + (size_t)(r0 - 2) * 4096 + c);
        w2 = *(const f16x8*)(upg + (size_t)(r0 - 1) * 4096 + c);
    }
#pragma unroll 4
    for (int i = 0; i < 16; ++i) {
        const size_t row = (size_t)(r0 + i);
        const f16x8 w3 = *(const f16x8*)(upg + row * 4096 + c);
        const f16x8 g  = *(const f16x8*)(upg + row * 4096 + 2048 + c);
        f16x8 o;
#pragma unroll
        for (int j = 0; j < 8; ++j) {
            float a = bias[j];
            a = fmaf((float)w0[j], tap[j][0], a);
            a = fmaf((float)w1[j], tap[j][1], a);
            a = fmaf((float)w2[j], tap[j][2], a);
            a = fmaf((float)w3[j], tap[j][3], a);
            o[j] = (f16)(silu_f((float)g[j]) * silu_f(a));
        }
        *(f16x8*)(upg + row * 4096 + 2048 + c) = o;
        w0 = w1; w1 = w2; w2 = w3;
    }
}

// ---------------- 4a. per-chunk outer products: GT[b][h][ch][e][d] = (K^T V)^T --
// Output TRANSPOSED (GT[e][d] = sum_c V[c][e] K[c][d]) so gscan_y's y1 B-operand
// (wants [col j][k d] rows) reads it naturally.
__global__ __launch_bounds__(256) void gscan_g_k(const f16* __restrict__ qkv,
                                                 f16* __restrict__ GT)
{
    __shared__ float Ks[4096];
    __shared__ float Vs[4096];
    const int t = threadIdx.x, ch = blockIdx.x, h = blockIdx.y, b = blockIdx.z;
    const int r = t >> 2, c16 = (t & 3) * 16;
    const f16* kp = qkv + ((size_t)b * SEQL + ch * 64 + r) * 3072 + DM + h * 64 + c16;
#pragma unroll
    for (int i = 0; i < 2; ++i) {
        const f16x8 kv = *(const f16x8*)(kp + 8 * i);
        const f16x8 vv = *(const f16x8*)(kp + DM + 8 * i);
#pragma unroll
        for (int j = 0; j < 8; ++j) {
            Ks[r * 64 + c16 + 8 * i + j] = (float)kv[j];
            Vs[r * 64 + c16 + 8 * i + j] = (float)vv[j];
        }
    }
    __syncthreads();
    const int e4 = (t >> 4) * 4, d4 = (t & 15) * 4;
    float4 ag[4] = {};
#pragma unroll 4
    for (int c = 0; c < 64; ++c) {
        float va[4];
        *(float4*)va = *(const float4*)(Vs + c * 64 + e4);
        const float4 ka = *(const float4*)(Ks + c * 64 + d4);
        ag[0].x = fmaf(va[0], ka.x, ag[0].x); ag[0].y = fmaf(va[0], ka.y, ag[0].y);
        ag[0].z = fmaf(va[0], ka.z, ag[0].z); ag[0].w = fmaf(va[0], ka.w, ag[0].w);
        ag[1].x = fmaf(va[1], ka.x, ag[1].x); ag[1].y = fmaf(va[1], ka.y, ag[1].y);
        ag[1].z = fmaf(va[1], ka.z, ag[1].z); ag[1].w = fmaf(va[1], ka.w, ag[1].w);
        ag[2].x = fmaf(va[2], ka.x, ag[2].x); ag[2].y = fmaf(va[2], ka.y, ag[2].y);
        ag[2].z = fmaf(va[2], ka.z, ag[2].z); ag[2].w = fmaf(va[2], ka.w, ag[2].w);
        ag[3].x = fmaf(va[3], ka.x, ag[3].x); ag[3].y = fmaf(va[3], ka.y, ag[3].y);
        ag[3].z = fmaf(va[3], ka.z, ag[3].z); ag[3].w = fmaf(va[3], ka.w, ag[3].w);
    }
    f16* go = GT + (((size_t)b * 16 + h) * 64 + ch) * 4096 + e4 * 64 + d4;
#pragma unroll
    for (int i = 0; i < 4; ++i) {
        f16x4 o;
        o[0] = (f16)ag[i].x; o[1] = (f16)ag[i].y;
        o[2] = (f16)ag[i].z; o[3] = (f16)ag[i].w;
        *(f16x4*)(go + i * 64) = o;
    }
}

// ---------------- 4b. in-place exclusive prefix over chunks (f16x2, fp32 carry) -
__global__ __launch_bounds__(256) void gprefix_k(f16* __restrict__ G)
{
    const int bh = blockIdx.x >> 3, sl = blockIdx.x & 7;
    f16x2* p = (f16x2*)(G + (size_t)bh * 64 * 4096) + sl * 256 + threadIdx.x;
    float r0 = 0.0f, r1 = 0.0f;
#pragma unroll 4
    for (int ch = 0; ch < 64; ++ch) {
        const f16x2 g = *p;
        f16x2 o; o[0] = (f16)r0; o[1] = (f16)r1;
        *p = o;
        r0 += (float)g[0]; r1 += (float)g[1];
        p += 2048;
    }
}

// ---------------- 4c. per-chunk read via MFMA: y = q*M_excl + tril(q k^T) v -----
// 256 thr = 4 waves; wave w owns row-tile c in [w*16, w*16+16).
// sc = q k^T : A=q natural [c][d], B=k natural [e][d] ([col][k] as MFMA wants).
// y1 = q M   : B=GT rows [j][d] (why gscan_g writes transposed).
// y2 = sc v  : A=sc row-major (reg->LDS with tril mask), B=vT (scalar-transposed).
// All LDS tiles use the GEMM's 16B-chunk XOR swizzle (chunk ^ ((row>>1)&3)).
__global__ __launch_bounds__(256) void gscan_y_k(const f16* __restrict__ qkv,
                                                 const f16* __restrict__ GT,
                                                 f16* __restrict__ y)
{
    __shared__ __align__(16) char lds[40960];
    f16* Qs = (f16*)lds;             // [64][64] 8KB
    f16* Ks = (f16*)(lds + 8192);
    f16* Ms = (f16*)(lds + 16384);
    f16* Vt = (f16*)(lds + 24576);   // vT[j][e]
    f16* Ss = (f16*)(lds + 32768);   // sc[c][e]

    const int t = threadIdx.x, ch = blockIdx.x, h = blockIdx.y, b = blockIdx.z;
    const int lane = t & 63, w = t >> 6;
    const int kb = lane >> 4, lr16 = lane & 15;

    // ---- stage: rows r = t>>2, data chunks c0, c0+1 (each 8 f16)
    const int r = t >> 2;
    const int c0 = (t & 3) * 2;
    const int rkey = (r >> 1) & 3;
    const f16* qp = qkv + ((size_t)b * SEQL + ch * 64 + r) * 3072 + h * 64;
    const f16* mp = GT + (((size_t)b * 16 + h) * 64 + ch) * 4096 + r * 64;
#pragma unroll
    for (int cc = 0; cc < 2; ++cc) {
        const int c = c0 + cc;
        const int sw = c ^ rkey;             // XOR affects low 2 bits only (halves kept)
        const f16x8 qv = *(const f16x8*)(qp + c * 8);
        const f16x8 kv = *(const f16x8*)(qp + DM + c * 8);
        const f16x8 vv = *(const f16x8*)(qp + 2 * DM + c * 8);
        const f16x8 mv = *(const f16x8*)(mp + c * 8);
        *(f16x8*)(Qs + r * 64 + sw * 8) = qv;
        *(f16x8*)(Ks + r * 64 + sw * 8) = kv;
        *(f16x8*)(Ms + r * 64 + sw * 8) = mv;
#pragma unroll
        for (int jj = 0; jj < 8; ++jj) {     // vT[j][e=r], e-chunk swizzled by j's key
            const int j = c * 8 + jj;
            Vt[j * 64 + ((((r >> 3) ^ ((j >> 1) & 3)) << 3) + (r & 7))] = vv[jj];
        }
    }
    __syncthreads();

    // ---- pass 1: sc tiles (tc=w, te=0..3)
    f16x8 af[2];
    {
        const int row = w * 16 + lr16;
        const int sz = (row >> 1) & 3;
        af[0] = *(const f16x8*)(Qs + row * 64 + (kb ^ sz) * 8);
        af[1] = *(const f16x8*)(Qs + row * 64 + (4 + (kb ^ sz)) * 8);
    }
    f32x4 accs[4];
#pragma unroll
    for (int te = 0; te < 4; ++te) accs[te] = (f32x4)0.0f;
#pragma unroll
    for (int te = 0; te < 4; ++te) {
        const int er = te * 16 + lr16;
        const int es = (er >> 1) & 3;
        const f16x8 b0 = *(const f16x8*)(Ks + er * 64 + (kb ^ es) * 8);
        const f16x8 b1 = *(const f16x8*)(Ks + er * 64 + (4 + (kb ^ es)) * 8);
        accs[te] = __builtin_amdgcn_mfma_f32_16x16x32_f16(af[0], b0, accs[te], 0, 0, 0);
        accs[te] = __builtin_amdgcn_mfma_f32_16x16x32_f16(af[1], b1, accs[te], 0, 0, 0);
    }
    // mask (keep e <= c) + store sc
#pragma unroll
    for (int te = 0; te < 4; ++te)
#pragma unroll
        for (int rr = 0; rr < 4; ++rr) {
            const int rc = w * 16 + kb * 4 + rr;
            const int ce = te * 16 + lr16;
            const float v = (ce <= rc) ? accs[te][rr] : 0.0f;
            Ss[rc * 64 + ((((ce >> 3) ^ ((rc >> 1) & 3)) << 3) + (ce & 7))] = (f16)v;
        }
    __syncthreads();

    // ---- pass 2: y tiles (tc=w, tj=0..3)
    f16x8 as2[2];
    {
        const int row = w * 16 + lr16;
        const int sz = (row >> 1) & 3;
        as2[0] = *(const f16x8*)(Ss + row * 64 + (kb ^ sz) * 8);
        as2[1] = *(const f16x8*)(Ss + row * 64 + (4 + (kb ^ sz)) * 8);
    }
    f32x4 accy[4];
#pragma unroll
    for (int tj = 0; tj < 4; ++tj) accy[tj] = (f32x4)0.0f;
#pragma unroll
    for (int tj = 0; tj < 4; ++tj) {
        const int jr = tj * 16 + lr16;
        const int js = (jr >> 1) & 3;
        const f16x8 m0 = *(const f16x8*)(Ms + jr * 64 + (kb ^ js) * 8);
        const f16x8 m1 = *(const f16x8*)(Ms + jr * 64 + (4 + (kb ^ js)) * 8);
        const f16x8 v0 = *(const f16x8*)(Vt + jr * 64 + (kb ^ js) * 8);
        const f16x8 v1 = *(const f16x8*)(Vt + jr * 64 + (4 + (kb ^ js)) * 8);
        accy[tj] = __builtin_amdgcn_mfma_f32_16x16x32_f16(af[0],  m0, accy[tj], 0, 0, 0);
        accy[tj] = __builtin_amdgcn_mfma_f32_16x16x32_f16(af[1],  m1, accy[tj], 0, 0, 0);
        accy[tj] = __builtin_amdgcn_mfma_f32_16x16x32_f16(as2[0], v0, accy[tj], 0, 0, 0);
        accy[tj] = __builtin_amdgcn_mfma_f32_16x16x32_f16(as2[1], v1, accy[tj], 0, 0, 0);
    }
    f16* yo = y + ((size_t)b * SEQL + ch * 64) * DM + h * 64;
#pragma unroll
    for (int tj = 0; tj < 4; ++tj)
#pragma unroll
        for (int rr = 0; rr < 4; ++rr) {
            const int rc = w * 16 + kb * 4 + rr;
            yo[(size_t)rc * DM + tj * 16 + lr16] = (f16)accy[tj][rr];
        }
}

// ---------------- launch --------------------------------------------------------
extern "C" void kernel_launch(void* const* d_in, const int* in_sizes, int n_in,
                              void* d_out, int out_size, void* d_ws, size_t ws_size,
                              hipStream_t stream)
{
    const float* x      = (const float*)d_in[0];
    const float* norm_w = (const float*)d_in[1];
    const float* w_up   = (const float*)d_in[2];
    const float* w_gate = (const float*)d_in[3];
    const float* w_down = (const float*)d_in[4];
    const float* conv_w = (const float*)d_in[5];
    const float* conv_b = (const float*)d_in[6];
    const float* wq     = (const float*)d_in[7];
    const float* wk     = (const float*)d_in[8];
    const float* wv     = (const float*)d_in[9];
    const float* wo     = (const float*)d_in[10];
    float* out = (float*)d_out;

    const size_t BIG_NEED = 247463936ull;
    const bool big = ws_size >= BIG_NEED;

    if (big) {
        char* p = (char*)d_ws;
        f16* upg = (f16*)p;               p += (size_t)NRALL * 4096 * 2;
        f16* hb  = (f16*)p;               p += (size_t)NRALL * DM * 2;
        char* fmtD   = p;                 p += (size_t)64 * 1024 * 64;
        char* fmtQKV = p;                 p += (size_t)32 * 3072 * 64;
        char* fmtO   = p;                 p += (size_t)32 * 1024 * 64;
        f16* xn = (f16*)p;                p += (size_t)NRALL * DM * 2;
        char* fmtUG  = p;
        f16* G = (f16*)xn;                // overlays xn+fmtUG (dead after up/gate GEMM)
        f16* qkvb = upg;
        f16* yb   = hb;

        prep_k<<<NRALL + 640, 256, 0, stream>>>(x, norm_w, xn, w_up, w_gate, w_down,
                                                wq, wk, wv, wo, fmtUG, fmtD, fmtQKV, fmtO);

        mg256_k<0><<<16 * 64, 1024, 0, stream>>>(xn, DM, fmtUG, upg, 4096, DM, 16, nullptr);
        conv_gate_k<<<NRALL / 16, 256, 0, stream>>>(upg, conv_w, conv_b);
        mg256_k<0><<<4 * 64, 1024, 0, stream>>>(upg + 2048, 4096, fmtD, hb, 1024, DI, 4, nullptr);
        mg256_k<1><<<12 * 64, 1024, 0, stream>>>(hb, DM, fmtQKV, qkvb, 3072, DM, 12, nullptr);

        gscan_g_k<<<dim3(64, 16, 4), 256, 0, stream>>>(qkvb, G);
        gprefix_k<<<512, 256, 0, stream>>>(G);
        gscan_y_k<<<dim3(64, 16, 4), 256, 0, stream>>>(qkvb, G, yb);

        mg256_k<2><<<4 * 64, 1024, 0, stream>>>(yb, DM, fmtO, out, 1024, DM, 4, x);
    } else {
        // compact per-batch path
        char* p = (char*)d_ws;
        f16* xn = (f16*)p;                p += (size_t)NRALL * DM * 2;
        f16* upg = (f16*)p;               p += (size_t)SEQL * 4096 * 2;
        f16* hb  = (f16*)p;               p += (size_t)SEQL * DM * 2;
        f16* G = (f16*)p;                 p += (size_t)16 * 64 * 4096 * 2;
        char* fmtUG  = p;                 p += (size_t)32 * 4096 * 64;
        char* fmtD   = p;                 p += (size_t)64 * 1024 * 64;
        char* fmtQKV = p;                 p += (size_t)32 * 3072 * 64;
        char* fmtO   = p;
        f16* qkvb = upg;
        f16* yb   = hb;

        prep_k<<<NRALL + 640, 256, 0, stream>>>(x, norm_w, xn, w_up, w_gate, w_down,
                                                wq, wk, wv, wo, fmtUG, fmtD, fmtQKV, fmtO);

        for (int b = 0; b < 4; ++b) {
            const f16* xnb = xn + (size_t)b * SEQL * DM;
            mg256_k<0><<<16 * 16, 1024, 0, stream>>>(xnb, DM, fmtUG, upg, 4096, DM, 16, nullptr);
            conv_gate_k<<<SEQL / 16, 256, 0, stream>>>(upg, conv_w, conv_b);
            mg256_k<0><<<4 * 16, 1024, 0, stream>>>(upg + 2048, 4096, fmtD, hb, 1024, DI, 4, nullptr);
            mg256_k<1><<<12 * 16, 1024, 0, stream>>>(hb, DM, fmtQKV, qkvb, 3072, DM, 12, nullptr);
            gscan_g_k<<<dim3(64, 16, 1), 256, 0, stream>>>(qkvb, G);
            gprefix_k<<<128, 256, 0, stream>>>(G);
            gscan_y_k<<<dim3(64, 16, 1), 256, 0, stream>>>(qkvb, G, yb);
            mg256_k<2><<<4 * 16, 1024, 0, stream>>>(yb, DM, fmtO,
                                                    out + (size_t)b * SEQL * DM, 1024, DM, 4,
                                                    x + (size_t)b * SEQL * DM);
        }
    }
}